// Round 1
// baseline (953.381 us; speedup 1.0000x reference)
//
#include <hip/hip_runtime.h>
#include <stdint.h>

typedef __attribute__((ext_vector_type(8))) short bf16x8_t;
typedef __attribute__((ext_vector_type(4))) float f32x4_t;
typedef __attribute__((ext_vector_type(4))) unsigned int u32x4_t;

#define B_ 16
#define C_ 128
#define O_ 256
#define H_ 96
#define W_ 96
#define HO_ 92
#define WO_ 92

// workspace offsets (bytes), total ~76.2 MB
#define XMU_OFF 0UL
#define XSG_OFF 37748736UL
#define WP_OFF  75497472UL
#define W2P_OFF 77135872UL
#define SP_OFF  78774272UL
#define T_OFF   78775296UL
#define S_OFF   79365120UL

__device__ __forceinline__ unsigned short f2bf(float f) {
  unsigned u = __float_as_uint(f);
  u += 0x7fffu + ((u >> 16) & 1u);   // RNE (inputs finite)
  return (unsigned short)(u >> 16);
}

#if defined(__has_builtin)
#if __has_builtin(__builtin_amdgcn_global_load_lds)
#define USE_GLL 1
#endif
#endif
#ifndef USE_GLL
#define USE_GLL 0
#endif

// 16B per lane: LDS dest = wave-uniform base + lane*16 (HW rule); global addr per-lane.
__device__ __forceinline__ void stage16(unsigned short* lds_base, const unsigned short* gp, int lane) {
#if USE_GLL
  __builtin_amdgcn_global_load_lds(
      (const __attribute__((address_space(1))) void*)gp,
      (__attribute__((address_space(3))) void*)lds_base, 16, 0, 0);
#else
  *((u32x4_t*)lds_base + lane) = *(const u32x4_t*)gp;
#endif
}

// ---------------- prep kernels ----------------

__global__ void k_sp(const float* __restrict__ wsig, float* __restrict__ sp) {
  int o = threadIdx.x;  // 256
  float a = fmaxf(wsig[o], -88.0f);
  sp[o] = log1pf(expf(a));
}

// pack W -> [t25][cc4][o][32c] bf16, and W^2 likewise
__global__ void k_packw(const float* __restrict__ W, unsigned short* __restrict__ Wp,
                        unsigned short* __restrict__ W2p) {
  int gid = blockIdx.x * 256 + threadIdx.x;  // < 819200
  int ci  = gid & 31;
  int o   = (gid >> 5) & 255;
  int cc4 = (gid >> 13) & 3;
  int t25 = gid >> 15;
  int c = cc4 * 32 + ci;
  float w = W[((size_t)o * 128 + c) * 25 + t25];
  Wp[gid]  = f2bf(w);
  W2p[gid] = f2bf(w * w);
}

// NCHW fp32 -> NHWC bf16 (one (b,h) slab per block; LDS transpose, pad 97 for banks)
__global__ void k_cast(const float* __restrict__ mu, const float* __restrict__ sg,
                       unsigned short* __restrict__ Xmu, unsigned short* __restrict__ Xsg) {
  __shared__ float sl[128 * 97];
  int bh = blockIdx.x;
  int b = bh / 96, h = bh - b * 96;
  const float* src = blockIdx.y ? sg : mu;
  unsigned short* dst = blockIdx.y ? Xsg : Xmu;
  int tid = threadIdx.x;
#pragma unroll
  for (int i = 0; i < 12; ++i) {
    int f4 = tid + i * 256;            // 3072 float4 chunks
    int c = f4 / 24, w4 = f4 - c * 24;
    f32x4_t v = *(const f32x4_t*)(src + (((size_t)b * 128 + c) * 96 + h) * 96 + w4 * 4);
    float* s = sl + c * 97 + w4 * 4;
    s[0] = v.x; s[1] = v.y; s[2] = v.z; s[3] = v.w;
  }
  __syncthreads();
  unsigned short* drow = dst + ((size_t)b * 96 + h) * (size_t)(96 * 128);
#pragma unroll
  for (int i = 0; i < 6; ++i) {
    int chunk = tid + i * 256;         // 1536 chunks of 8 bf16
    int w = chunk >> 4;
    int c0 = (chunk & 15) * 8;
    u32x4_t pk;
#pragma unroll
    for (int e = 0; e < 4; ++e) {
      unsigned lo = f2bf(sl[(c0 + 2 * e) * 97 + w]);
      unsigned hi = f2bf(sl[(c0 + 2 * e + 1) * 97 + w]);
      pk[e] = lo | (hi << 16);
    }
    *(u32x4_t*)(drow + (size_t)w * 128 + c0) = pk;
  }
}

// t[b,h,w] = sum_c (sigma + mu^2)
__global__ void k_t(const float* __restrict__ mu, const float* __restrict__ sg, float* __restrict__ t) {
  int gid = blockIdx.x * 256 + threadIdx.x;  // 147456
  int b = gid / 9216;
  int r = gid - b * 9216;
  const float* mp  = mu + (size_t)b * 128 * 9216 + r;
  const float* sgp = sg + (size_t)b * 128 * 9216 + r;
  float s = 0.f;
#pragma unroll 4
  for (int c = 0; c < 128; ++c) {
    float m = mp[(size_t)c * 9216];
    s += sgp[(size_t)c * 9216] + m * m;
  }
  t[gid] = s;
}

// S[b,y,x] = 5x5 box sum of t
__global__ void k_S(const float* __restrict__ t, float* __restrict__ S) {
  int gid = blockIdx.x * 256 + threadIdx.x;
  if (gid >= 135424) return;
  int b = gid / 8464;
  int r = gid - b * 8464;
  int y = r / 92;
  int x = r - y * 92;
  const float* tp = t + (size_t)b * 9216 + (size_t)y * 96 + x;
  float s = 0.f;
#pragma unroll
  for (int kh = 0; kh < 5; ++kh) {
    const float* row = tp + kh * 96;
#pragma unroll
    for (int kw = 0; kw < 5; ++kw) s += row[kw];
  }
  S[gid] = s;
}

// ---------------- main conv (implicit GEMM, bf16 MFMA) ----------------
// block = one output row (b,y): TM=96 (x padded, store x<92), TN=256 (full O)
// 4 waves split O into 64 each; K-loop = 25 (kh,kw) x 4 c-chunks of 32
__global__ __launch_bounds__(256, 2) void k_conv(
    const unsigned short* __restrict__ Xmu, const unsigned short* __restrict__ Xsg,
    const unsigned short* __restrict__ Wp,  const unsigned short* __restrict__ W2p,
    const float* __restrict__ bias, const float* __restrict__ sp,
    const float* __restrict__ Sb, float* __restrict__ out) {
  __shared__ char smem[25600];                       // A(6144) + B(16384); epi reuses 25600
  unsigned short* Alds = (unsigned short*)smem;      // [96 x][32 c] 64B rows, quarter-swizzled
  unsigned short* Blds = (unsigned short*)(smem + 6144);  // [256 o][32 c]

  const int mode = blockIdx.y;                       // 0: mu path, 1: sigma path
  const unsigned short* X   = mode ? Xsg : Xmu;
  const unsigned short* Wt0 = mode ? W2p : Wp;

  const int bid = blockIdx.x;
  const int b = bid / HO_;
  const int y = bid - b * HO_;

  const int tid  = threadIdx.x;
  const int wv   = tid >> 6;
  const int lane = tid & 63;
  const int l15  = lane & 15;
  const int g4   = lane >> 4;

  // frag-read offsets (ushorts), swizzle q_phys = g ^ ((row>>1)&3)
  int aoff[6], boff[4];
#pragma unroll
  for (int im = 0; im < 6; ++im) {
    int x = im * 16 + l15;
    int qp = g4 ^ ((x >> 1) & 3);
    aoff[im] = x * 32 + qp * 8;
  }
#pragma unroll
  for (int in = 0; in < 4; ++in) {
    int o = wv * 64 + in * 16 + l15;
    int qp = g4 ^ ((o >> 1) & 3);
    boff[in] = o * 32 + qp * 8;
  }

  const int lq   = lane >> 2;   // staging: row within 16-row chunk
  const int qp_s = lane & 3;    // staging: physical quarter

  f32x4_t acc[6][4];
#pragma unroll
  for (int im = 0; im < 6; ++im)
#pragma unroll
    for (int in = 0; in < 4; ++in)
      acc[im][in] = (f32x4_t)0.0f;

  for (int t25 = 0; t25 < 25; ++t25) {
    const int kh = t25 / 5;
    const int kw = t25 - kh * 5;
    const unsigned short* Xrow = X + ((size_t)(b * H_ + y + kh) * W_) * C_;
    const unsigned short* Wt = Wt0 + (size_t)t25 * 4 * 8192;
    for (int cc4 = 0; cc4 < 4; ++cc4) {
      __syncthreads();
      // 22 x 1KB staging chunks (A:6, B:16) round-robin across waves
#pragma unroll
      for (int jj = 0; jj < 6; ++jj) {
        const int j = wv + jj * 4;
        if (j < 22) {
          if (j < 6) {
            int x  = j * 16 + lq;
            int ql = qp_s ^ ((x >> 1) & 3);
            int w_in = min(x + kw, 95);            // x>=92 is padding; clamped, never stored
            const unsigned short* gp = Xrow + w_in * C_ + cc4 * 32 + ql * 8;
            stage16(Alds + j * 512, gp, lane);
          } else {
            int jb = j - 6;
            int o  = jb * 16 + lq;
            int ql = qp_s ^ ((o >> 1) & 3);
            const unsigned short* gp = Wt + cc4 * 8192 + o * 32 + ql * 8;
            stage16(Blds + jb * 512, gp, lane);
          }
        }
      }
      __syncthreads();
      bf16x8_t af[6], bfr[4];
#pragma unroll
      for (int im = 0; im < 6; ++im)
        af[im] = *(const bf16x8_t*)(Alds + aoff[im]);
#pragma unroll
      for (int in = 0; in < 4; ++in)
        bfr[in] = *(const bf16x8_t*)(Blds + boff[in]);
#pragma unroll
      for (int im = 0; im < 6; ++im)
#pragma unroll
        for (int in = 0; in < 4; ++in)
          acc[im][in] = __builtin_amdgcn_mfma_f32_16x16x32_bf16(af[im], bfr[in], acc[im][in], 0, 0, 0);
    }
  }

  // epilogue: transpose through LDS so stores are x-contiguous dwordx4
  float* epi = (float*)smem + wv * 1600;            // [16 o][100 x-padded] per wave
  const size_t outbase = (size_t)mode * ((size_t)B_ * O_ * HO_ * WO_);
  const int orow = lane >> 2, seg = lane & 3;
  const float* Srow = Sb + ((size_t)b * HO_ + y) * WO_;
#pragma unroll
  for (int in = 0; in < 4; ++in) {
    __syncthreads();
#pragma unroll
    for (int im = 0; im < 6; ++im)
#pragma unroll
      for (int r = 0; r < 4; ++r)
        epi[l15 * 100 + im * 16 + g4 * 4 + r] = acc[im][in][r];  // C/D: col=lane&15(=o), row=g4*4+r(=x)
    __syncthreads();
    const int o = wv * 64 + in * 16 + orow;
    const float scal = mode ? sp[o] : bias[o];
    const float* erow = epi + orow * 100;
    float* optr = out + outbase + ((size_t)(b * O_ + o) * HO_ + y) * WO_;
#pragma unroll
    for (int jq = 0; jq < 6; ++jq) {
      int q = jq * 4 + seg;
      if (q < 23) {                                  // 92 = 23*4, drop x>=92 padding
        f32x4_t v = *(const f32x4_t*)(erow + q * 4);
        int x = q * 4;
        if (mode) {
          f32x4_t s4 = *(const f32x4_t*)(Srow + x);
          v = (scal * s4 + v) * 0.001f;
        } else {
          v = v + scal;
        }
        *(f32x4_t*)(optr + x) = v;
      }
    }
  }
}

extern "C" void kernel_launch(void* const* d_in, const int* in_sizes, int n_in,
                              void* d_out, int out_size, void* d_ws, size_t ws_size,
                              hipStream_t stream) {
  const float* mu   = (const float*)d_in[0];
  const float* sg   = (const float*)d_in[1];
  const float* W    = (const float*)d_in[2];
  const float* bias = (const float*)d_in[3];
  const float* wsig = (const float*)d_in[4];
  float* out = (float*)d_out;
  char* ws = (char*)d_ws;

  unsigned short* Xmu = (unsigned short*)(ws + XMU_OFF);
  unsigned short* Xsg = (unsigned short*)(ws + XSG_OFF);
  unsigned short* Wp  = (unsigned short*)(ws + WP_OFF);
  unsigned short* W2p = (unsigned short*)(ws + W2P_OFF);
  float* sp = (float*)(ws + SP_OFF);
  float* tb = (float*)(ws + T_OFF);
  float* Sb = (float*)(ws + S_OFF);

  k_sp<<<1, 256, 0, stream>>>(wsig, sp);
  k_packw<<<3200, 256, 0, stream>>>(W, Wp, W2p);
  k_cast<<<dim3(1536, 2), 256, 0, stream>>>(mu, sg, Xmu, Xsg);
  k_t<<<576, 256, 0, stream>>>(mu, sg, tb);
  k_S<<<529, 256, 0, stream>>>(tb, Sb);
  k_conv<<<dim3(B_ * HO_, 2), 256, 0, stream>>>(Xmu, Xsg, Wp, W2p, bias, sp, Sb, out);
}

// Round 2
// 788.855 us; speedup vs baseline: 1.2086x; 1.2086x over previous
//
#include <hip/hip_runtime.h>
#include <stdint.h>

typedef __attribute__((ext_vector_type(8))) short bf16x8_t;
typedef __attribute__((ext_vector_type(4))) float f32x4_t;
typedef __attribute__((ext_vector_type(4))) unsigned int u32x4_t;

#define B_ 16
#define C_ 128
#define O_ 256
#define H_ 96
#define W_ 96
#define HO_ 92
#define WO_ 92

// workspace offsets (bytes), total ~79.9 MB (same footprint as round 1)
#define XMU_OFF 0UL
#define XSG_OFF 37748736UL
#define WP_OFF  75497472UL
#define W2P_OFF 77135872UL
#define SP_OFF  78774272UL
#define T_OFF   78775296UL
#define S_OFF   79365120UL

__device__ __forceinline__ unsigned short f2bf(float f) {
  unsigned u = __float_as_uint(f);
  u += 0x7fffu + ((u >> 16) & 1u);   // RNE (inputs finite)
  return (unsigned short)(u >> 16);
}

#if defined(__has_builtin)
#if __has_builtin(__builtin_amdgcn_global_load_lds)
#define USE_GLL 1
#endif
#endif
#ifndef USE_GLL
#define USE_GLL 0
#endif

// 16B per lane: LDS dest = wave-uniform base + lane*16 (HW rule); global addr per-lane.
__device__ __forceinline__ void stage16(unsigned short* lds_base, const unsigned short* gp, int lane) {
#if USE_GLL
  __builtin_amdgcn_global_load_lds(
      (const __attribute__((address_space(1))) void*)gp,
      (__attribute__((address_space(3))) void*)lds_base, 16, 0, 0);
#else
  *((u32x4_t*)lds_base + lane) = *(const u32x4_t*)gp;
#endif
}

// ---------------- prep kernels ----------------

__global__ void k_sp(const float* __restrict__ wsig, float* __restrict__ sp) {
  int o = threadIdx.x;  // 256
  float a = fmaxf(wsig[o], -88.0f);
  sp[o] = log1pf(expf(a));
}

__global__ void k_zero(float* __restrict__ t) {
  t[blockIdx.x * 256 + threadIdx.x] = 0.0f;  // 576 blocks x 256 = 147456
}

// pack W -> [t25][cc4][o][32c] bf16, and W^2 likewise
__global__ void k_packw(const float* __restrict__ W, unsigned short* __restrict__ Wp,
                        unsigned short* __restrict__ W2p) {
  int gid = blockIdx.x * 256 + threadIdx.x;  // < 819200
  int ci  = gid & 31;
  int o   = (gid >> 5) & 255;
  int cc4 = (gid >> 13) & 3;
  int t25 = gid >> 15;
  int c = cc4 * 32 + ci;
  float w = W[((size_t)o * 128 + c) * 25 + t25];
  Wp[gid]  = f2bf(w);
  W2p[gid] = f2bf(w * w);
}

// NCHW fp32 -> NHWC bf16 + fused per-row channel sums:
//   mu-block adds sum_c mu^2 to t[b,h,w]; sg-block adds sum_c sg.
// Two atomic contributors per address (a+b == b+a) -> deterministic.
__global__ void k_cast(const float* __restrict__ mu, const float* __restrict__ sg,
                       unsigned short* __restrict__ Xmu, unsigned short* __restrict__ Xsg,
                       float* __restrict__ t) {
  __shared__ float sl[128 * 97];
  __shared__ float part[192];
  int bh = blockIdx.x;
  int b = bh / 96, h = bh - b * 96;
  const int is_mu = (blockIdx.y == 0);
  const float* src = is_mu ? mu : sg;
  unsigned short* dst = is_mu ? Xmu : Xsg;
  int tid = threadIdx.x;
#pragma unroll
  for (int i = 0; i < 12; ++i) {
    int f4 = tid + i * 256;            // 3072 float4 chunks
    int c = f4 / 24, w4 = f4 - c * 24;
    f32x4_t v = *(const f32x4_t*)(src + (((size_t)b * 128 + c) * 96 + h) * 96 + w4 * 4);
    float* s = sl + c * 97 + w4 * 4;
    s[0] = v.x; s[1] = v.y; s[2] = v.z; s[3] = v.w;
  }
  __syncthreads();
  unsigned short* drow = dst + ((size_t)b * 96 + h) * (size_t)(96 * 128);
#pragma unroll
  for (int i = 0; i < 6; ++i) {
    int chunk = tid + i * 256;         // 1536 chunks of 8 bf16
    int w = chunk >> 4;
    int c0 = (chunk & 15) * 8;
    u32x4_t pk;
#pragma unroll
    for (int e = 0; e < 4; ++e) {
      unsigned lo = f2bf(sl[(c0 + 2 * e) * 97 + w]);
      unsigned hi = f2bf(sl[(c0 + 2 * e + 1) * 97 + w]);
      pk[e] = lo | (hi << 16);
    }
    *(u32x4_t*)(drow + (size_t)w * 128 + c0) = pk;
  }
  // fused channel-sum partials (replaces k_t's 151 MB HBM re-read)
  if (tid < 192) {
    int half = tid / 96, w = tid - half * 96;
    float s = 0.f;
#pragma unroll 4
    for (int c = half * 64; c < half * 64 + 64; ++c) {
      float v = sl[c * 97 + w];
      s += is_mu ? v * v : v;
    }
    part[tid] = s;
  }
  __syncthreads();
  if (tid < 96)
    atomicAdd(&t[((size_t)b * 96 + h) * 96 + tid], part[tid] + part[96 + tid]);
}

// S[b,y,x] = 5x5 box sum of t
__global__ void k_S(const float* __restrict__ t, float* __restrict__ S) {
  int gid = blockIdx.x * 256 + threadIdx.x;
  if (gid >= 135424) return;
  int b = gid / 8464;
  int r = gid - b * 8464;
  int y = r / 92;
  int x = r - y * 92;
  const float* tp = t + (size_t)b * 9216 + (size_t)y * 96 + x;
  float s = 0.f;
#pragma unroll
  for (int kh = 0; kh < 5; ++kh) {
    const float* row = tp + kh * 96;
#pragma unroll
    for (int kw = 0; kw < 5; ++kw) s += row[kw];
  }
  S[gid] = s;
}

// ---------------- main conv (implicit GEMM, bf16 MFMA) ----------------
// block = one output row (b,y): TM=96 (x padded, store x<92), TN=256.
// A (input row, 96px x 128c = 24 KB) staged to LDS ONCE per kh, serves all
// 20 (kw,cc) k-steps. B (weights) read straight global->VGPR (L2-hot,
// perfectly coalesced 1 KB/wave-frag) -- never touches LDS.
// Barriers: 2 per kh (10/block) instead of 200; inner 20 steps barrier-free.
__global__ __launch_bounds__(256, 2) void k_conv(
    const unsigned short* __restrict__ Xmu, const unsigned short* __restrict__ Xsg,
    const unsigned short* __restrict__ Wp,  const unsigned short* __restrict__ W2p,
    const float* __restrict__ bias, const float* __restrict__ sp,
    const float* __restrict__ Sb, float* __restrict__ out) {
  __shared__ char smem[25600];                       // A row 24576 B; epi reuses 25600
  unsigned short* Alds = (unsigned short*)smem;      // [96 p][16 chunks of 16B], chunk^= (p&15)

  const int mode = blockIdx.y;                       // 0: mu path, 1: sigma path
  const unsigned short* X   = mode ? Xsg : Xmu;
  const unsigned short* Wt0 = mode ? W2p : Wp;

  const int bid = blockIdx.x;
  const int b = bid / HO_;
  const int y = bid - b * HO_;

  const int tid  = threadIdx.x;
  const int wv   = tid >> 6;
  const int lane = tid & 63;
  const int l15  = lane & 15;
  const int g4   = lane >> 4;

  // staging lane decomposition: 1 KB chunk = 4 pixels x 256 B
  const int p_st = lane >> 4;        // pixel within chunk
  const int q_st = lane & 15;        // physical 16B slot within 256B row

  f32x4_t acc[6][4];
#pragma unroll
  for (int im = 0; im < 6; ++im)
#pragma unroll
    for (int in = 0; in < 4; ++in)
      acc[im][in] = (f32x4_t)0.0f;

  const int bo = (wv * 64 + l15) * 32 + g4 * 8;      // B frag base offset (ushorts)

  for (int kh = 0; kh < 5; ++kh) {
    const unsigned short* Xrow = X + ((size_t)(b * H_ + y + kh) * W_) * C_;
    __syncthreads();                                 // prev kh's frag reads done
    // stage 24 chunks of 1 KB round-robin over 4 waves
#pragma unroll
    for (int jj = 0; jj < 6; ++jj) {
      const int j = wv + jj * 4;
      const int p = j * 4 + p_st;
      const int c0 = (q_st ^ (p & 15)) * 8;          // swizzled channel slot
      stage16(Alds + j * 512, Xrow + p * C_ + c0, lane);
    }
    __syncthreads();                                 // staged data visible
#pragma unroll
    for (int kw = 0; kw < 5; ++kw) {
      const unsigned short* Wt = Wt0 + (size_t)(kh * 5 + kw) * 32768;
      int prow[6], pxor[6];
#pragma unroll
      for (int im = 0; im < 6; ++im) {
        int p = im * 16 + l15 + kw;
        p = p < 95 ? p : 95;                         // x>=92 is padding, never stored
        prow[im] = p << 7;                           // row base in ushorts (128/row)
        pxor[im] = p & 15;
      }
#pragma unroll
      for (int cc = 0; cc < 4; ++cc) {
        bf16x8_t bfr[4];
#pragma unroll
        for (int in = 0; in < 4; ++in)
          bfr[in] = *(const bf16x8_t*)(Wt + cc * 8192 + in * 512 + bo);
        bf16x8_t af[6];
        const int cl = cc * 4 + g4;
#pragma unroll
        for (int im = 0; im < 6; ++im)
          af[im] = *(const bf16x8_t*)(Alds + prow[im] + ((cl ^ pxor[im]) << 3));
#pragma unroll
        for (int im = 0; im < 6; ++im)
#pragma unroll
          for (int in = 0; in < 4; ++in)
            acc[im][in] = __builtin_amdgcn_mfma_f32_16x16x32_bf16(af[im], bfr[in], acc[im][in], 0, 0, 0);
      }
    }
  }

  // epilogue: transpose through LDS so stores are x-contiguous dwordx4
  float* epi = (float*)smem + wv * 1600;             // [16 o][100 x-padded] per wave
  const size_t outbase = (size_t)mode * ((size_t)B_ * O_ * HO_ * WO_);
  const int orow = lane >> 2, seg = lane & 3;
  const float* Srow = Sb + ((size_t)b * HO_ + y) * WO_;
#pragma unroll
  for (int in = 0; in < 4; ++in) {
    __syncthreads();
#pragma unroll
    for (int im = 0; im < 6; ++im)
#pragma unroll
      for (int r = 0; r < 4; ++r)
        epi[l15 * 100 + im * 16 + g4 * 4 + r] = acc[im][in][r];  // C/D: col=lane&15(=o), row=g4*4+r(=x)
    __syncthreads();
    const int o = wv * 64 + in * 16 + orow;
    const float scal = mode ? sp[o] : bias[o];
    const float* erow = epi + orow * 100;
    float* optr = out + outbase + ((size_t)(b * O_ + o) * HO_ + y) * WO_;
#pragma unroll
    for (int jq = 0; jq < 6; ++jq) {
      int q = jq * 4 + seg;
      if (q < 23) {                                  // 92 = 23*4, drop x>=92 padding
        f32x4_t v = *(const f32x4_t*)(erow + q * 4);
        int x = q * 4;
        if (mode) {
          f32x4_t s4 = *(const f32x4_t*)(Srow + x);
          v = (scal * s4 + v) * 0.001f;
        } else {
          v = v + scal;
        }
        *(f32x4_t*)(optr + x) = v;
      }
    }
  }
}

extern "C" void kernel_launch(void* const* d_in, const int* in_sizes, int n_in,
                              void* d_out, int out_size, void* d_ws, size_t ws_size,
                              hipStream_t stream) {
  const float* mu   = (const float*)d_in[0];
  const float* sg   = (const float*)d_in[1];
  const float* W    = (const float*)d_in[2];
  const float* bias = (const float*)d_in[3];
  const float* wsig = (const float*)d_in[4];
  float* out = (float*)d_out;
  char* ws = (char*)d_ws;

  unsigned short* Xmu = (unsigned short*)(ws + XMU_OFF);
  unsigned short* Xsg = (unsigned short*)(ws + XSG_OFF);
  unsigned short* Wp  = (unsigned short*)(ws + WP_OFF);
  unsigned short* W2p = (unsigned short*)(ws + W2P_OFF);
  float* sp = (float*)(ws + SP_OFF);
  float* tb = (float*)(ws + T_OFF);
  float* Sb = (float*)(ws + S_OFF);

  k_sp<<<1, 256, 0, stream>>>(wsig, sp);
  k_zero<<<576, 256, 0, stream>>>(tb);
  k_packw<<<3200, 256, 0, stream>>>(W, Wp, W2p);
  k_cast<<<dim3(1536, 2), 256, 0, stream>>>(mu, sg, Xmu, Xsg, tb);
  k_S<<<529, 256, 0, stream>>>(tb, Sb);
  k_conv<<<dim3(B_ * HO_, 2), 256, 0, stream>>>(Xmu, Xsg, Wp, W2p, bias, sp, Sb, out);
}